// Round 2
// baseline (166.060 us; speedup 1.0000x reference)
//
#include <hip/hip_runtime.h>

// out[m,u] = x2[m] + w2[u] - 2 * sum_k x[m,k] * w[k,u]
// x[32768, 128] f32, w[128, 1024] f32, out[32768, 1024] f32
#define M_TOT 32768
#define K_DIM 128
#define U_TOT 1024
#define BM 128
#define BN 128

typedef short s16x8 __attribute__((ext_vector_type(8)));   // 8 bf16 (4 VGPRs)
typedef float f32x4 __attribute__((ext_vector_type(4)));

// round-to-nearest-even fp32 -> bf16 (as ushort)
__device__ inline unsigned int f2bf(float f) {
    union { float f; unsigned int u; } v; v.f = f;
    return (v.u + 0x7FFFu + ((v.u >> 16) & 1u)) >> 16;
}

// async global->LDS, 16B per lane; LDS dest = wave-uniform base + lane*16
__device__ inline void async_load16(const void* g, void* l) {
    __builtin_amdgcn_global_load_lds((const __attribute__((address_space(1))) void*)g,
                                     (__attribute__((address_space(3))) void*)l,
                                     16, 0, 0);
}

// Swizzled 16B-slot index within a [128][128] bf16 tile (row = 256 B = 16 slots).
// byte ^= (row&15)<<4 : bijective within each row, kills the stride-256B
// bank aliasing on ds_read_b128.
__device__ inline int swz(int row, int j) { return (row << 4) | (j ^ (row & 15)); }

// w -> w^T bf16 [1024][128] + w2. One wave per u-column. 256 blocks, ~0.75 MB traffic.
__global__ __launch_bounds__(256) void prep_w(
    const float* __restrict__ w, unsigned int* __restrict__ wt, float* __restrict__ w2)
{
    const int lane = threadIdx.x & 63;
    const int u = (blockIdx.x << 2) + (threadIdx.x >> 6);
    const float a = w[(size_t)(2 * lane) * U_TOT + u];
    const float b = w[(size_t)(2 * lane + 1) * U_TOT + u];
    float s = a * a + b * b;
    #pragma unroll
    for (int off = 32; off; off >>= 1) s += __shfl_xor(s, off);
    wt[u * 64 + lane] = f2bf(a) | (f2bf(b) << 16);
    if (lane == 0) w2[u] = s;
}

// Fused GEMM: 128x128 tile, FULL K=128 resident in LDS, one barrier per block.
// A is reg-staged fp32->bf16 (x2 computed in fp32 in registers, handed to the
// epilogue by shuffle: wave wv owns output rows [wv*32, wv*32+32) == the rows
// it staged). B is staged by global_load_lds with pre-swizzled global source.
__global__ __launch_bounds__(256, 2) void gemm_kernel(
    const float* __restrict__ x, const unsigned short* __restrict__ wt,
    const float* __restrict__ w2, float* __restrict__ out)
{
    __shared__ __align__(16) unsigned short As[BM * K_DIM];   // 32 KB, swizzled
    __shared__ __align__(16) unsigned short Bs[BN * K_DIM];   // 32 KB, swizzled

    const int tid = threadIdx.x;
    const int wv = tid >> 6;
    const int lane = tid & 63;

    // XCD-aware mapping: the 8 u-tiles of one m-tile land on the SAME XCD,
    // consecutively in dispatch order -> x m-tile fetched once per XCD L2.
    const int b = blockIdx.x;
    const int mt = (b & 7) * 32 + ((b >> 3) >> 3);   // 0..255
    const int ut = (b >> 3) & 7;                     // 0..7
    const int m0 = mt * BM;
    const int u0 = ut * BN;

    // ---- B stage: async global->LDS, linear dest + inverse-swizzled source ----
    #pragma unroll
    for (int i = 0; i < 8; ++i) {
        const int p = i * 256 + tid;                 // physical 16B slot
        const int row = p >> 4;
        const int j = (p & 15) ^ (row & 15);         // logical slot-in-row
        async_load16(wt + ((size_t)(u0 + row) << 7) + j * 8,
                     &Bs[(i * 256 + (tid & 192)) * 8]);   // wave-uniform base
    }

    // ---- A stage: coalesced fp32 loads, in-reg convert + x2, swizzled ds_write ----
    const int ar = tid >> 1;                         // row 0..127 (wave wv: rows wv*32..+32)
    const int ah = tid & 1;                          // k-half
    const float4* xs4 = (const float4*)(x + ((size_t)(m0 + ar) << 7) + (ah << 6));
    float ssum = 0.f;
    #pragma unroll
    for (int c = 0; c < 8; ++c) {
        const float4 v0 = xs4[2 * c];
        const float4 v1 = xs4[2 * c + 1];
        ssum += v0.x * v0.x + v0.y * v0.y + v0.z * v0.z + v0.w * v0.w
              + v1.x * v1.x + v1.y * v1.y + v1.z * v1.z + v1.w * v1.w;
        uint4 pk;
        pk.x = f2bf(v0.x) | (f2bf(v0.y) << 16);
        pk.y = f2bf(v0.z) | (f2bf(v0.w) << 16);
        pk.z = f2bf(v1.x) | (f2bf(v1.y) << 16);
        pk.w = f2bf(v1.z) | (f2bf(v1.w) << 16);
        *(uint4*)&As[swz(ar, (ah << 3) + c) * 8] = pk;
    }
    ssum += __shfl_xor(ssum, 1);                     // both half-row lanes: full fp32 x2

    __syncthreads();                                 // the ONLY barrier (drains vm+lgkm)

    // ---- MFMA: wave = 32x128 band; acc[2][8], 64 MFMAs ----
    const int col = lane & 15;
    const int quad = lane >> 4;
    const int wm = wv << 5;

    f32x4 acc[2][8] = {};
    #pragma unroll
    for (int kk = 0; kk < 4; ++kk) {
        const int jj = (kk << 2) + quad;             // logical 16B slot = k-offset/8
        s16x8 af[2], bfr[8];
        #pragma unroll
        for (int a = 0; a < 2; ++a)
            af[a] = *(const s16x8*)&As[swz(wm + a * 16 + col, jj) * 8];
        #pragma unroll
        for (int n = 0; n < 8; ++n)
            bfr[n] = *(const s16x8*)&Bs[swz(n * 16 + col, jj) * 8];
        #pragma unroll
        for (int a = 0; a < 2; ++a)
            #pragma unroll
            for (int n = 0; n < 8; ++n)
                acc[a][n] = __builtin_amdgcn_mfma_f32_16x16x32_bf16(af[a], bfr[n], acc[a][n], 0, 0, 0);
    }

    // ---- Epilogue: C/D layout col=lane&15, row=quad*4+reg ----
    const int orow = quad << 2;
    #pragma unroll
    for (int a = 0; a < 2; ++a) {
        const int lr = wm + a * 16 + orow;           // local row base in tile
        float xsq[4];
        #pragma unroll
        for (int r = 0; r < 4; ++r)
            xsq[r] = __shfl(ssum, (a * 16 + orow + r) << 1);  // lane 2*localrow staged it
        #pragma unroll
        for (int n = 0; n < 8; ++n) {
            const int u = u0 + n * 16 + col;
            const float wsq = w2[u];
            float* op = out + (size_t)(m0 + lr) * U_TOT + u;
            #pragma unroll
            for (int r = 0; r < 4; ++r)
                op[(size_t)r * U_TOT] = xsq[r] + wsq - 2.0f * acc[a][n][r];
        }
    }
}

// Fallback (no workspace): correct fp32 path, used only if ws_size is too small.
__global__ __launch_bounds__(256) void fallback_kernel(
    const float* __restrict__ x, const float* __restrict__ w,
    float* __restrict__ out)
{
    __shared__ float xrow[K_DIM];
    const int m = blockIdx.x;
    const int tid = threadIdx.x;
    if (tid < K_DIM) xrow[tid] = x[(size_t)m * K_DIM + tid];
    __syncthreads();
    float x2 = 0.f;
    #pragma unroll
    for (int k = 0; k < K_DIM; ++k) x2 += xrow[k] * xrow[k];
    #pragma unroll
    for (int uu = 0; uu < 4; ++uu) {
        const int u = uu * 256 + tid;
        float dot = 0.f, w2 = 0.f;
        for (int k = 0; k < K_DIM; ++k) {
            const float wv = w[(size_t)k * U_TOT + u];
            dot += xrow[k] * wv;
            w2 += wv * wv;
        }
        out[(size_t)m * U_TOT + u] = x2 + w2 - 2.0f * dot;
    }
}

extern "C" void kernel_launch(void* const* d_in, const int* in_sizes, int n_in,
                              void* d_out, int out_size, void* d_ws, size_t ws_size,
                              hipStream_t stream) {
    const float* x = (const float*)d_in[0];
    const float* w = (const float*)d_in[1];
    float* out = (float*)d_out;

    // ws layout: wt bf16[1024*128] | w2 f32[1024]
    const size_t need = (size_t)U_TOT * K_DIM * 2 + (size_t)U_TOT * 4;
    if (ws_size < need) {
        fallback_kernel<<<M_TOT, 256, 0, stream>>>(x, w, out);
        return;
    }

    unsigned short* wt = (unsigned short*)d_ws;
    float* w2 = (float*)(wt + (size_t)U_TOT * K_DIM);

    prep_w<<<U_TOT / 4, 256, 0, stream>>>(w, (unsigned int*)wt, w2);
    gemm_kernel<<<(M_TOT / BM) * (U_TOT / BN), 256, 0, stream>>>(x, wt, w2, out);
}

// Round 3
// 152.416 us; speedup vs baseline: 1.0895x; 1.0895x over previous
//
#include <hip/hip_runtime.h>

// out[m,u] = x2[m] + w2[u] - 2 * sum_k x[m,k] * w[k,u]
// x[32768, 128] f32, w[128, 1024] f32, out[32768, 1024] f32
#define M_TOT 32768
#define K_DIM 128
#define U_TOT 1024

#define GBM 64      // rows per pipeline iteration
#define GBN 128     // cols per block (full u-stripe of the tile)
#define NMS 8       // m-subtiles per block -> block covers 512 rows x 128 cols

typedef short s16x8 __attribute__((ext_vector_type(8)));    // 8 bf16 (4 VGPRs)
typedef float f32x16 __attribute__((ext_vector_type(16)));  // 32x32 MFMA acc

// round-to-nearest-even fp32 -> bf16 (as ushort)
__device__ inline unsigned int f2bf(float f) {
    union { float f; unsigned int u; } v; v.f = f;
    return (v.u + 0x7FFFu + ((v.u >> 16) & 1u)) >> 16;
}

// async global->LDS, 16B per lane; LDS dest = wave-uniform base + lane*16
__device__ inline void async_load16(const void* g, void* l) {
    __builtin_amdgcn_global_load_lds((const __attribute__((address_space(1))) void*)g,
                                     (__attribute__((address_space(3))) void*)l,
                                     16, 0, 0);
}

// prep: x -> bf16 row-major xb + x2 (blocks 0..4095, 8 rows each);
//       w -> w^T bf16 wt + w2 (blocks 4096..4351, 4 u each).
__global__ __launch_bounds__(256) void prep_kernel(
    const float* __restrict__ x, const float* __restrict__ w,
    unsigned int* __restrict__ xb, unsigned int* __restrict__ wt,
    float* __restrict__ x2, float* __restrict__ w2)
{
    const int lane = threadIdx.x & 63;
    const int lc = lane & 31;
    if (blockIdx.x < 4096) {
        const int wv = threadIdx.x >> 6;
        const int row = (blockIdx.x << 3) + (wv << 1) + (lane >> 5);
        const float4 v = ((const float4*)(x + (size_t)row * K_DIM))[lc];
        float s = v.x * v.x + v.y * v.y + v.z * v.z + v.w * v.w;
        #pragma unroll
        for (int off = 16; off; off >>= 1) s += __shfl_xor(s, off);
        uint2 pk;
        pk.x = f2bf(v.x) | (f2bf(v.y) << 16);
        pk.y = f2bf(v.z) | (f2bf(v.w) << 16);
        ((uint2*)xb)[(size_t)row * 32 + lc] = pk;   // k = lc*4 .. lc*4+3
        if (lc == 0) x2[row] = s;
    } else {
        const int u = ((blockIdx.x - 4096) << 2) + (threadIdx.x >> 6);
        const float a = w[(size_t)(2 * lane) * U_TOT + u];
        const float b = w[(size_t)(2 * lane + 1) * U_TOT + u];
        float s = a * a + b * b;
        #pragma unroll
        for (int off = 32; off; off >>= 1) s += __shfl_xor(s, off);
        wt[u * 64 + lane] = f2bf(a) | (f2bf(b) << 16);
        if (lane == 0) w2[u] = s;
    }
}

// GEMM: 512 blocks x 512 threads (8 waves) -> whole grid resident at 2 blocks/CU.
// Block (ut, msb): cols ut*128..+127, rows msb*512..+511 in 8 subtiles of 64.
// B (128x128 bf16) staged once by DMA, read once into registers (32 VGPR/lane).
// A double-buffered by DMA (2x16 KB), one barrier per subtile (2-phase pipeline).
// Wave wv: rows (wv>>2)*32, cols (wv&3)*32 -> one 32x32x16 MFMA chain, K=128.
__global__ __launch_bounds__(512, 4) void gemm_kernel(
    const unsigned short* __restrict__ xb, const unsigned short* __restrict__ wt,
    const float* __restrict__ x2, const float* __restrict__ w2,
    float* __restrict__ out)
{
    __shared__ __align__(16) unsigned short Bs[GBN * K_DIM];      // 32 KB, swizzled
    __shared__ __align__(16) unsigned short As[2][GBM * K_DIM];   // 2 x 16 KB, swizzled

    const int tid = threadIdx.x;
    const int wv = tid >> 6;
    const int lane = tid & 63;
    const int lc = lane & 31;
    const int hi = lane >> 5;

    // XCD mapping: b%8 = XCD; XCD j owns msb j*8..j*8+7 (contiguous 4096 rows),
    // its 8 ut-blocks per msb dispatch consecutively -> xb served by its L2.
    const int b = blockIdx.x;
    const int ut = (b >> 3) & 7;
    const int msb = (b & 7) * 8 + (b >> 6);
    const int u0 = ut * GBN;
    const int mbase = msb * (GBM * NMS);

    // ---- prologue DMA (linear LDS dest + inverse-swizzled global source) ----
    #pragma unroll
    for (int i = 0; i < 4; ++i) {                       // B: 32 KB
        const int p = (wv * 4 + i) * 64 + lane;         // physical 16B slot
        const int row = p >> 4;
        const int j = (p & 15) ^ (row & 15);
        async_load16(wt + ((size_t)(u0 + row) << 7) + j * 8, &Bs[(p & ~63) * 8]);
    }
    #pragma unroll
    for (int i = 0; i < 2; ++i) {                       // A[0]: 16 KB
        const int p = (wv * 2 + i) * 64 + lane;
        const int row = p >> 4;
        const int j = (p & 15) ^ (row & 15);
        async_load16(xb + ((size_t)(mbase + row) << 7) + j * 8, &As[0][(p & ~63) * 8]);
    }

    const int wr = wv >> 2;                             // 0..1  (row group)
    const int wc = wv & 3;                              // 0..3  (col group)
    const float w2v = w2[u0 + wc * 32 + lc];            // per-lane output col

    __syncthreads();                                    // B + A[0] resident

    // ---- B fragments to registers: B[k][col], col=lc, k = hi*8 + st*16 ----
    s16x8 bfrag[8];
    #pragma unroll
    for (int st = 0; st < 8; ++st) {
        const int row = wc * 32 + lc;
        const int j0 = (st << 1) + hi;
        bfrag[st] = *(const s16x8*)&Bs[((row << 4) + (j0 ^ (row & 15))) * 8];
    }

    #pragma unroll
    for (int ms = 0; ms < NMS; ++ms) {
        // issue next A-tile DMA first: flies under this subtile's compute+stores
        if (ms + 1 < NMS) {
            #pragma unroll
            for (int i = 0; i < 2; ++i) {
                const int p = (wv * 2 + i) * 64 + lane;
                const int row = p >> 4;
                const int j = (p & 15) ^ (row & 15);
                async_load16(xb + ((size_t)(mbase + (ms + 1) * GBM + row) << 7) + j * 8,
                             &As[(ms + 1) & 1][(p & ~63) * 8]);
            }
        }

        const int mb = mbase + ms * GBM + wr * 32;
        const float x2row = x2[mb + lc];                // 128B broadcast load

        f32x16 acc = {};
        #pragma unroll
        for (int st = 0; st < 8; ++st) {
            const int row = wr * 32 + lc;
            const int j0 = (st << 1) + hi;
            const s16x8 af = *(const s16x8*)&As[ms & 1][((row << 4) + (j0 ^ (row & 15))) * 8];
            acc = __builtin_amdgcn_mfma_f32_32x32x16_bf16(af, bfrag[st], acc, 0, 0, 0);
        }

        // C/D 32x32: col=lane&31, row=(r&3)+8*(r>>2)+4*hi (m74/m101-verified).
        // Each store: 32 lanes x 4B = full 128B line (x2 rows per inst).
        float* op = out + (size_t)mb * U_TOT + u0 + wc * 32 + lc;
        #pragma unroll
        for (int r = 0; r < 16; ++r) {
            const int t = (r & 3) + ((r >> 2) << 3);
            const float xs = __shfl(x2row, t + (hi << 2) + (lane & 32));
            op[(size_t)(t + (hi << 2)) * U_TOT] = xs + w2v - 2.0f * acc[r];
        }
        if (ms + 1 < NMS) __syncthreads();              // one drain+barrier per subtile
    }
}

// Fallback (no workspace): correct fp32 path, used only if ws_size is too small.
__global__ __launch_bounds__(256) void fallback_kernel(
    const float* __restrict__ x, const float* __restrict__ w,
    float* __restrict__ out)
{
    __shared__ float xrow[K_DIM];
    const int m = blockIdx.x;
    const int tid = threadIdx.x;
    if (tid < K_DIM) xrow[tid] = x[(size_t)m * K_DIM + tid];
    __syncthreads();
    float x2 = 0.f;
    #pragma unroll
    for (int k = 0; k < K_DIM; ++k) x2 += xrow[k] * xrow[k];
    #pragma unroll
    for (int uu = 0; uu < 4; ++uu) {
        const int u = uu * 256 + tid;
        float dot = 0.f, w2 = 0.f;
        for (int k = 0; k < K_DIM; ++k) {
            const float wv = w[(size_t)k * U_TOT + u];
            dot += xrow[k] * wv;
            w2 += wv * wv;
        }
        out[(size_t)m * U_TOT + u] = x2 + w2 - 2.0f * dot;
    }
}

extern "C" void kernel_launch(void* const* d_in, const int* in_sizes, int n_in,
                              void* d_out, int out_size, void* d_ws, size_t ws_size,
                              hipStream_t stream) {
    const float* x = (const float*)d_in[0];
    const float* w = (const float*)d_in[1];
    float* out = (float*)d_out;

    // ws layout: xb bf16[32768*128] | wt bf16[1024*128] | x2 f32[32768] | w2 f32[1024]
    const size_t need = (size_t)M_TOT * K_DIM * 2 + (size_t)U_TOT * K_DIM * 2
                      + (size_t)M_TOT * 4 + (size_t)U_TOT * 4;
    if (ws_size < need) {
        fallback_kernel<<<M_TOT, 256, 0, stream>>>(x, w, out);
        return;
    }

    unsigned short* xb = (unsigned short*)d_ws;
    unsigned short* wt = xb + (size_t)M_TOT * K_DIM;
    float* x2 = (float*)(wt + (size_t)U_TOT * K_DIM);
    float* w2 = x2 + M_TOT;

    prep_kernel<<<4096 + 256, 256, 0, stream>>>(x, w, (unsigned int*)xb,
                                                (unsigned int*)wt, x2, w2);
    gemm_kernel<<<(M_TOT / (GBM * NMS)) * (U_TOT / GBN), 512, 0, stream>>>(xb, wt, x2, w2, out);
}